// Round 3
// baseline (462.265 us; speedup 1.0000x reference)
//
#include <hip/hip_runtime.h>
#include <math.h>

#define N 4096
#define ROUNDS 12           // components at least halve per round: 4096 -> 1 guaranteed
#define INFKEY 0xFFFFFFFFFFFFFFFFULL
#define LCAP 48             // candidate-list capacity per row

// ---- workspace layout (bytes) ----
#define WS_CAND(ws)   ((unsigned long long*)((char*)(ws) + 0))        // u64[2N]   64 KB
#define WS_COMP(ws)   ((int*)((char*)(ws) + 65536))                   // int[2N]   32 KB
#define WS_EDGES(ws)  ((int2*)((char*)(ws) + 98304))                  // int2[2N]  64 KB
#define WS_PARENT(ws) ((int*)((char*)(ws) + 163840))                  // int[2N]   32 KB
#define WS_META(ws)   ((int*)((char*)(ws) + 196608))                  // int[4]: done0,done1,ecnt0,ecnt1
#define WS_RCNT(ws)   ((int*)((char*)(ws) + 196864))                  // int[2N]   32 KB
#define WS_RTHR(ws)   ((float*)((char*)(ws) + 229632))                // float[2N] 32 KB
#define WS_FLAGS(ws)  ((int*)((char*)(ws) + 262400))                  // int[2N]   32 KB
#define WS_LISTS(ws)  ((unsigned long long*)((char*)(ws) + 295168))   // u64[2N*LCAP] 3 MB
// total ~3.4 MB

// cand key: (float_bits(w) << 24) | (u << 12) | v    (56 bits, u64 atomicMin)
// list entry: (float_bits(w) << 12) | j              (44 bits)
// distances >= 0 -> float bit pattern order-preserving; weights assumed unique.

// One wave per row. Streams the full matrix ONCE: computes per-row threshold
// T = min + 0.25*(mean-min), compacts entries < T into the candidate list
// (ballot compaction). Also folds in all state init (comp/cand/meta).
__global__ __launch_bounds__(1024) void build_kernel(const float* __restrict__ D1,
                                                     const float* __restrict__ D2,
                                                     int* __restrict__ comp,
                                                     unsigned long long* __restrict__ cand,
                                                     int* __restrict__ meta,
                                                     int* __restrict__ rowcount,
                                                     float* __restrict__ rthresh,
                                                     unsigned long long* __restrict__ lists) {
    const int gb = blockIdx.x;   // 512 blocks: 256 per matrix
    const int tid = threadIdx.x;

    // ---- folded init (consumed only by later dispatches) ----
    if (gb < 8) cand[gb * 1024 + tid] = INFKEY;                       // 8192 u64
    else if (gb < 10) {                                               // 8192 ints of comp
        int i4 = (gb - 8) * 1024 + tid;
        int b = i4 * 4;
        ((int4*)comp)[i4] = make_int4(b & (N - 1), (b + 1) & (N - 1),
                                      (b + 2) & (N - 1), (b + 3) & (N - 1));
    } else if (gb == 10 && tid < 4) meta[tid] = 0;

    const int m = gb >> 8;
    const int wid = tid >> 6, lane = tid & 63;
    const int row = (gb & 255) * 16 + wid;
    const float* __restrict__ Drow = (m ? D2 : D1) + (size_t)row * N;
    const float INF = __builtin_inff();

    // load full row into registers: 16 independent float4 loads (high MLP)
    float4 v[16];
#pragma unroll
    for (int it = 0; it < 16; ++it)
        v[it] = *(const float4*)(Drow + it * 256 + lane * 4);

    // min (excluding exact-zero self) and sum (self adds 0, harmless)
    float mn = INF, sm = 0.f;
#pragma unroll
    for (int it = 0; it < 16; ++it) {
        float a = v[it].x, b = v[it].y, c = v[it].z, d = v[it].w;
        mn = fminf(mn, a > 0.f ? a : INF);
        mn = fminf(mn, b > 0.f ? b : INF);
        mn = fminf(mn, c > 0.f ? c : INF);
        mn = fminf(mn, d > 0.f ? d : INF);
        sm += a + b + c + d;
    }
#pragma unroll
    for (int off = 32; off > 0; off >>= 1) {
        mn = fminf(mn, __shfl_xor(mn, off, 64));
        sm += __shfl_xor(sm, off, 64);
    }
    const float mean = sm * (1.f / 4095.f);
    const float T = mn + 0.25f * (mean - mn);

    // ballot-compact entries < T (and > 0: excludes the zero diagonal)
    unsigned long long* lp = lists + (size_t)(m * N + row) * LCAP;
    const unsigned long long ltmask = (lane == 0) ? 0ULL : ((~0ULL) >> (64 - lane));
    int base = 0;
#pragma unroll
    for (int it = 0; it < 16; ++it) {
        float e[4] = {v[it].x, v[it].y, v[it].z, v[it].w};
#pragma unroll
        for (int s = 0; s < 4; ++s) {
            float x = e[s];
            int j = it * 256 + lane * 4 + s;
            bool p = (x > 0.f) && (x < T);
            unsigned long long bm = __ballot(p);
            if (p) {
                int pos = base + __popcll(bm & ltmask);
                if (pos < LCAP)
                    lp[pos] = ((unsigned long long)__float_as_uint(x) << 12) | (unsigned)j;
            }
            base += __popcll(bm);
        }
    }
    if (lane == 0) {
        rowcount[m * N + row] = base;   // may exceed LCAP -> overflow marker
        rthresh[m * N + row] = T;
    }
}

// One thread per row: exact row cross-min from the candidate list, or flag
// for rescan (1 = exhausted with valid bound T, 2 = overflow, bound invalid).
__global__ __launch_bounds__(1024) void list_scan(const int* __restrict__ comp,
                                                  unsigned long long* __restrict__ cand,
                                                  const int* __restrict__ meta,
                                                  const int* __restrict__ rowcount,
                                                  const unsigned long long* __restrict__ lists,
                                                  int* __restrict__ flags) {
    const int m = blockIdx.x >> 2;
    if (meta[m]) return;
    const int* __restrict__ cm = comp + m * N;

    __shared__ int scomp[N];
    const int tid = threadIdx.x;
    for (int i = tid; i < N / 4; i += 1024)
        ((int4*)scomp)[i] = ((const int4*)cm)[i];
    __syncthreads();

    const int row = (blockIdx.x & 3) * 1024 + tid;
    const int c = scomp[row];
    const int cnt = rowcount[m * N + row];
    int flag;
    if (cnt > LCAP) {
        flag = 2;
    } else {
        unsigned long long best = INFKEY;
        const unsigned long long* lp = lists + (size_t)(m * N + row) * LCAP;
        for (int k = 0; k < cnt; ++k) {
            unsigned long long e = lp[k];
            int j = (int)(e & 0xFFF);
            if (scomp[j] != c && e < best) best = e;
        }
        if (best != INFKEY) {
            unsigned long long key = ((best >> 12) << 24) | ((unsigned long long)row << 12) | (best & 0xFFF);
            atomicMin(&cand[m * N + c], key);
            flag = 0;
        } else {
            flag = 1;   // exhausted: true cross-min >= T_row
        }
    }
    flags[m * N + row] = flag;
}

// One wave per row: full 16KB row rescan, only for flagged rows that could
// still beat the component's current candidate (T_row < w_c), or overflow rows.
__global__ __launch_bounds__(1024) void rescan_kernel(const float* __restrict__ D1,
                                                      const float* __restrict__ D2,
                                                      const int* __restrict__ comp,
                                                      unsigned long long* __restrict__ cand,
                                                      const int* __restrict__ meta,
                                                      const int* __restrict__ flags,
                                                      const float* __restrict__ rthresh) {
    const int m = blockIdx.x >> 8;
    if (meta[m]) return;
    const int wid = threadIdx.x >> 6, lane = threadIdx.x & 63;
    const int row = (blockIdx.x & 255) * 16 + wid;
    const int flag = flags[m * N + row];
    if (!flag) return;                        // wave-uniform
    const int* __restrict__ cm = comp + m * N;
    const int c = cm[row];
    if (flag == 1) {
        unsigned long long cc = cand[m * N + c];
        float w = (cc == INFKEY) ? __builtin_inff()
                                 : __uint_as_float((unsigned)(cc >> 24));
        if (!(rthresh[m * N + row] < w)) return;   // cannot beat -> skip
    }
    const float* __restrict__ Drow = (m ? D2 : D1) + (size_t)row * N;
    unsigned long long best = INFKEY;
    for (int j0 = lane * 4; j0 < N; j0 += 256) {
        float4 d = *(const float4*)(Drow + j0);
        int4 cj = *(const int4*)(cm + j0);
        if (cj.x != c) {
            unsigned long long k = ((unsigned long long)__float_as_uint(d.x) << 12) | (unsigned)(j0 + 0);
            if (k < best) best = k;
        }
        if (cj.y != c) {
            unsigned long long k = ((unsigned long long)__float_as_uint(d.y) << 12) | (unsigned)(j0 + 1);
            if (k < best) best = k;
        }
        if (cj.z != c) {
            unsigned long long k = ((unsigned long long)__float_as_uint(d.z) << 12) | (unsigned)(j0 + 2);
            if (k < best) best = k;
        }
        if (cj.w != c) {
            unsigned long long k = ((unsigned long long)__float_as_uint(d.w) << 12) | (unsigned)(j0 + 3);
            if (k < best) best = k;
        }
    }
#pragma unroll
    for (int off = 32; off > 0; off >>= 1) {
        unsigned long long o = __shfl_xor(best, off, 64);
        if (o < best) best = o;
    }
    if (lane == 0 && best != INFKEY) {
        unsigned long long key = ((best >> 12) << 24) | ((unsigned long long)row << 12) | (best & 0xFFF);
        atomicMin(&cand[m * N + c], key);
    }
}

// One workgroup per matrix: hook components along min edges, record MST edges,
// pointer-jump compress, detect completion, re-init cand.  (unchanged, proven)
__global__ __launch_bounds__(1024) void boruvka_hook(int* __restrict__ comp,
                                                     unsigned long long* __restrict__ cand,
                                                     int* __restrict__ link,
                                                     int2* __restrict__ edges,
                                                     int* __restrict__ meta) {
    const int m = blockIdx.x;
    if (meta[m]) return;
    int* __restrict__ cm = comp + m * N;
    unsigned long long* __restrict__ cd = cand + m * N;
    int* __restrict__ lk = link + m * N;
    int2* __restrict__ ed = edges + m * N;
    int* __restrict__ ecnt = meta + 2 + m;
    const int tid = threadIdx.x;

    for (int c = tid; c < N; c += 1024) {
        int l = cm[c];
        if (l == c) {
            unsigned long long k = cd[c];
            if (k != INFKEY) {
                int v = (int)(k & 0xFFF);
                int u = (int)((k >> 12) & 0xFFF);
                int t = cm[v];
                unsigned long long tk = cd[t];
                int mutual = 0;
                if (tk != INFKEY) {
                    int tv = (int)(tk & 0xFFF);
                    mutual = (cm[tv] == c);
                }
                if (mutual) {
                    if (c < t) {
                        int idx = atomicAdd(ecnt, 1);
                        ed[idx] = make_int2(u, v);
                    } else {
                        l = t;
                    }
                } else {
                    int idx = atomicAdd(ecnt, 1);
                    ed[idx] = make_int2(u, v);
                    l = t;
                }
            }
        }
        lk[c] = l;
    }
    __syncthreads();
    for (int c = tid; c < N; c += 1024) cm[c] = lk[c];
    __syncthreads();
    for (int it = 0; it < 12; ++it) {
        for (int c = tid; c < N; c += 1024) cm[c] = cm[cm[c]];
        __syncthreads();
    }
    __shared__ int cnt;
    if (tid == 0) cnt = 0;
    __syncthreads();
    int local = 0;
    for (int c = tid; c < N; c += 1024) local += (cm[c] == c) ? 1 : 0;
    atomicAdd(&cnt, local);
    __syncthreads();
    if (tid == 0 && cnt == 1) meta[m] = 1;
    for (int c = tid; c < N; c += 1024) cd[c] = INFKEY;
}

// Orient MST edges toward node 0 (level-synchronous BFS in LDS).  (unchanged)
__global__ __launch_bounds__(1024) void root_kernel(const int2* __restrict__ edges,
                                                    const int* __restrict__ meta,
                                                    int* __restrict__ parent) {
    const int m = blockIdx.x;
    const int2* __restrict__ ed = edges + m * N;
    int* __restrict__ p = parent + m * N;
    const int ec = meta[2 + m];

    __shared__ int2 se[N];
    __shared__ int sp[N];
    __shared__ unsigned char kprev[N], kcur[N];
    __shared__ int changed;
    const int tid = threadIdx.x;

    for (int i = tid; i < ec; i += 1024) se[i] = ed[i];
    for (int i = tid; i < N; i += 1024) { sp[i] = 0; kprev[i] = 0; kcur[i] = 0; }
    __syncthreads();
    if (tid == 0) { kprev[0] = 1; kcur[0] = 1; }
    __syncthreads();

    for (int pass = 0; pass < N; ++pass) {
        if (tid == 0) changed = 0;
        __syncthreads();
        for (int e = tid; e < ec; e += 1024) {
            int2 uv = se[e];
            unsigned char ku = kprev[uv.x], kv = kprev[uv.y];
            if (ku && !kv) { sp[uv.y] = uv.x; kcur[uv.y] = 1; changed = 1; }
            else if (kv && !ku) { sp[uv.x] = uv.y; kcur[uv.x] = 1; changed = 1; }
        }
        __syncthreads();
        int go = changed;
        __syncthreads();
        if (!go) break;
        for (int i = tid; i < N; i += 1024) kprev[i] = kcur[i];
        __syncthreads();
    }
    for (int i = tid; i < N; i += 1024) p[i] = sp[i];
}

__global__ __launch_bounds__(1024) void finalize_kernel(const float* __restrict__ D1,
                                                        const float* __restrict__ D2,
                                                        const int* __restrict__ parent,
                                                        float* __restrict__ out) {
    __shared__ float rs12[16], rs21[16];
    __shared__ int rm[16];
    const int tid = threadIdx.x;
    const int* p1 = parent;
    const int* p2 = parent + N;

    float s12 = 0.f, s21 = 0.f;
    int mcnt = 0;
    for (int c = 1 + tid; c < N; c += 1024) {
        int a = p1[c];
        int b = p2[c];
        float e1 = D1[(size_t)a * N + c] - D2[(size_t)a * N + c];
        float e2 = D2[(size_t)b * N + c] - D1[(size_t)b * N + c];
        s12 += e1 * e1;
        s21 += e2 * e2;
        mcnt += (a == b) ? 1 : 0;
    }
#pragma unroll
    for (int off = 32; off > 0; off >>= 1) {
        s12 += __shfl_xor(s12, off, 64);
        s21 += __shfl_xor(s21, off, 64);
        mcnt += __shfl_xor(mcnt, off, 64);
    }
    const int wid = tid >> 6, lane = tid & 63;
    if (lane == 0) { rs12[wid] = s12; rs21[wid] = s21; rm[wid] = mcnt; }
    __syncthreads();
    if (tid == 0) {
        float a = 0.f, b = 0.f;
        int mm = 0;
#pragma unroll
        for (int w = 0; w < 16; ++w) { a += rs12[w]; b += rs21[w]; mm += rm[w]; }
        float d12 = sqrtf(a);
        float d21 = sqrtf(b);
        out[0] = d12 + d21;
        out[1] = d12;
        out[2] = d21;
        out[3] = (float)mm;
    }
}

extern "C" void kernel_launch(void* const* d_in, const int* in_sizes, int n_in,
                              void* d_out, int out_size, void* d_ws, size_t ws_size,
                              hipStream_t stream) {
    const float* D1 = (const float*)d_in[0];
    const float* D2 = (const float*)d_in[1];

    unsigned long long* cand = WS_CAND(d_ws);
    int* comp = WS_COMP(d_ws);
    int2* edges = WS_EDGES(d_ws);
    int* parent = WS_PARENT(d_ws);
    int* meta = WS_META(d_ws);
    int* rcnt = WS_RCNT(d_ws);
    float* rthr = WS_RTHR(d_ws);
    int* flags = WS_FLAGS(d_ws);
    unsigned long long* lists = WS_LISTS(d_ws);

    build_kernel<<<512, 1024, 0, stream>>>(D1, D2, comp, cand, meta, rcnt, rthr, lists);

    for (int r = 0; r < ROUNDS; ++r) {
        list_scan<<<8, 1024, 0, stream>>>(comp, cand, meta, rcnt, lists, flags);
        rescan_kernel<<<512, 1024, 0, stream>>>(D1, D2, comp, cand, meta, flags, rthr);
        boruvka_hook<<<2, 1024, 0, stream>>>(comp, cand, parent, edges, meta);
    }

    root_kernel<<<2, 1024, 0, stream>>>(edges, meta, parent);
    finalize_kernel<<<1, 1024, 0, stream>>>(D1, D2, parent, (float*)d_out);
}